// Round 9
// baseline (304.523 us; speedup 1.0000x reference)
//
#include <hip/hip_runtime.h>
#include <hip/hip_cooperative_groups.h>

namespace cg = cooperative_groups;

typedef _Float16 half8 __attribute__((ext_vector_type(8)));
typedef float floatx4 __attribute__((ext_vector_type(4)));
typedef unsigned int uint2v __attribute__((ext_vector_type(2)));

#define NSPLIT 64
#define KS 64
#define DIM 2048
#define NROW 128            // 2*KS rows of T per split
#define BK 128              // k-panel width
#define KSPL 4              // k-chunks per split -> 256 blocks, exactly 1/CU
#define KCH (DIM / KSPL)    // 512
#define NKC_A (KCH / BK)    // 4 panels per block
#define SST 152             // stage row stride (fp16): 304 B, 16B-aligned, 2-way banks (free)
#define GSZ (NROW * NROW)   // 16384 floats per partial-gram slab
#define NBLK (NSPLIT * KSPL)          // 256 blocks
#define GT2_OFF (NBLK * GSZ)          // per-block sum-of-gram scalars (256 floats)
#define PART_OFF (GT2_OFF + NBLK)     // per-block partials (256 x float4)

// Slab layout fragment-major: float index = wave*1024 + acc*256 + lane*4 + reg
// wave = (row>>5)*4 + (col>>5); acc = ((row>>4)&1)*2 + ((col>>4)&1);
// lane = ((row&15)>>2)*16 + (col&15); reg = row&3.

__device__ __forceinline__ unsigned int pk16(float a, float b) {
  return __builtin_bit_cast(unsigned int, __builtin_amdgcn_cvt_pkrtz(a, b));
}

__global__ __launch_bounds__(1024) void mmd_fused(const float* __restrict__ src,
                                                  const float* __restrict__ tgt,
                                                  float* __restrict__ ws,
                                                  float* __restrict__ out) {
  __shared__ __align__(16) _Float16 stage[NROW * SST];  // ~38 KB
  __shared__ float red[16];
  __shared__ float sqv[NROW];
  __shared__ float bcast[8];
  __shared__ float redm[16];
  __shared__ float quad2[2];
  __shared__ float fr[4][5];

  cg::grid_group grid = cg::this_grid();

  const int b = blockIdx.x;
  const int p = b >> 2;
  const int c = b & (KSPL - 1);
  const int tid = threadIdx.x;
  const int lane = tid & 63;
  const int wave = tid >> 6;

  // ================= PHASE 1: partial gram (identical math to R7) =================
  {
    const int srow = tid >> 3;
    const int c4 = (tid & 7) * 4;
    const float* rowp = ((srow < KS) ? (src + (size_t)(p * KS + srow) * DIM)
                                     : (tgt + (size_t)(p * KS + (srow - KS)) * DIM)) +
                        c * KCH;

    const int wr = (wave >> 2) * 32;
    const int wc = (wave & 3) * 32;
    const int frr = lane & 15;
    const int fk = (lane >> 4) * 8;

    floatx4 acc00 = {0.f, 0.f, 0.f, 0.f};
    floatx4 acc01 = {0.f, 0.f, 0.f, 0.f};
    floatx4 acc10 = {0.f, 0.f, 0.f, 0.f};
    floatx4 acc11 = {0.f, 0.f, 0.f, 0.f};

    float4 f0, f1, f2, f3;
#define LOADK(kc)                                      \
    do {                                               \
      const float* gp_ = rowp + (kc) * BK + c4;        \
      f0 = *(const float4*)(gp_);                      \
      f1 = *(const float4*)(gp_ + 32);                 \
      f2 = *(const float4*)(gp_ + 64);                 \
      f3 = *(const float4*)(gp_ + 96);                 \
    } while (0)

    LOADK(0);
    for (int kc = 0; kc < NKC_A; ++kc) {
      __syncthreads();
      {
        _Float16* sp = &stage[srow * SST + c4];
        *(uint2v*)(sp)      = (uint2v){pk16(f0.x, f0.y), pk16(f0.z, f0.w)};
        *(uint2v*)(sp + 32) = (uint2v){pk16(f1.x, f1.y), pk16(f1.z, f1.w)};
        *(uint2v*)(sp + 64) = (uint2v){pk16(f2.x, f2.y), pk16(f2.z, f2.w)};
        *(uint2v*)(sp + 96) = (uint2v){pk16(f3.x, f3.y), pk16(f3.z, f3.w)};
      }
      __syncthreads();
      if (kc + 1 < NKC_A) LOADK(kc + 1);  // prefetch next panel under MFMA
#pragma unroll
      for (int ks = 0; ks < 4; ++ks) {
        const int ko = ks * 32 + fk;
        half8 a0 = *(const half8*)&stage[(wr + frr) * SST + ko];
        half8 a1 = *(const half8*)&stage[(wr + 16 + frr) * SST + ko];
        half8 b0 = *(const half8*)&stage[(wc + frr) * SST + ko];
        half8 b1 = *(const half8*)&stage[(wc + 16 + frr) * SST + ko];
        acc00 = __builtin_amdgcn_mfma_f32_16x16x32_f16(a0, b0, acc00, 0, 0, 0);
        acc01 = __builtin_amdgcn_mfma_f32_16x16x32_f16(a0, b1, acc01, 0, 0, 0);
        acc10 = __builtin_amdgcn_mfma_f32_16x16x32_f16(a1, b0, acc10, 0, 0, 0);
        acc11 = __builtin_amdgcn_mfma_f32_16x16x32_f16(a1, b1, acc11, 0, 0, 0);
      }
    }
#undef LOADK

    // fragment-major slab store: contiguous dwordx4, no transpose
    float* wsp = ws + (size_t)b * GSZ + wave * 1024 + lane * 4;
    *(floatx4*)(wsp)       = acc00;
    *(floatx4*)(wsp + 256) = acc01;
    *(floatx4*)(wsp + 512) = acc10;
    *(floatx4*)(wsp + 768) = acc11;

    float gsum = 0.0f;
#pragma unroll
    for (int r = 0; r < 4; ++r) gsum += acc00[r] + acc01[r] + acc10[r] + acc11[r];
#pragma unroll
    for (int m = 1; m <= 32; m <<= 1) gsum += __shfl_xor(gsum, m, 64);
    if (lane == 0) red[wave] = gsum;
    __syncthreads();
    if (tid == 0) {
      float t = 0.0f;
      for (int w = 0; w < 16; ++w) t += red[w];
      ws[GT2_OFF + b] = t;
    }
  }

  __threadfence();
  grid.sync();  // all slabs + gsums visible device-wide

  // ================= PHASE 2: reduce (p, rb = c) — identical math to R7 =================
  {
    const int rb = c;
    const int row = rb * 32 + (tid >> 5);
    const int cg2 = tid & 31;  // cols cg2*4 .. cg2*4+3

    const float* sb = ws + (size_t)(p * KSPL) * GSZ;
    const int wv = ((row >> 5) << 2) + (cg2 >> 3);
    const int a = (((row >> 4) & 1) << 1) + ((cg2 >> 2) & 1);
    const int ln = (((row & 15) >> 2) << 4) + ((cg2 & 3) << 2);
    const int idx = wv * 1024 + a * 256 + ln * 4 + (row & 3);

    float g0 = 0.f, g1 = 0.f, g2 = 0.f, g3 = 0.f;
#pragma unroll
    for (int c8 = 0; c8 < KSPL; ++c8) {
      const float* bp = sb + (size_t)c8 * GSZ + idx;
      g0 += bp[0]; g1 += bp[4]; g2 += bp[8]; g3 += bp[12];
    }

    if (tid < NROW) {  // diagonal, same slab order -> exact l2_ii = 0
      const int i = tid;
      const int wd = (i >> 5) * 5;
      const int ad = ((i >> 4) & 1) * 3;
      const int lnd = (((i & 15) >> 2) << 4) + (i & 15);
      const int idxd = wd * 1024 + ad * 256 + lnd * 4 + (i & 3);
      float d = 0.0f;
#pragma unroll
      for (int c8 = 0; c8 < KSPL; ++c8) d += sb[(size_t)c8 * GSZ + idxd];
      sqv[i] = d;
    }
    if (tid < 2) quad2[tid] = 0.0f;
    __syncthreads();

    if (tid == 0) {
      float ssq = 0.0f;
      for (int i = 0; i < NROW; ++i) ssq += sqv[i];
      float gt = ws[GT2_OFF + p * 4 + 0] + ws[GT2_OFF + p * 4 + 1] +
                 ws[GT2_OFF + p * 4 + 2] + ws[GT2_OFF + p * 4 + 3];
      float suml2 = 2.0f * (float)NROW * ssq - 2.0f * gt;       // sum(l2) identity
      float bwv = suml2 / (float)(NROW * NROW - NROW) * 0.25f;  // /(n^2-n) /KERNEL_MUL^2
      float mult = 1.0f;
      for (int k = 0; k < 5; ++k) {
        bcast[k] = 1.0f / (bwv * mult + 1e-9f);
        mult *= 2.0f;
      }
    }
    __syncthreads();

    const float sqi = sqv[row];
    float l2r[4];
    float lmax = 0.0f;
    {
      const float gg[4] = {g0, g1, g2, g3};
#pragma unroll
      for (int k = 0; k < 4; ++k) {
        float v = sqi + sqv[cg2 * 4 + k] - 2.0f * gg[k];
        l2r[k] = v;
        lmax = fmaxf(lmax, v);
      }
    }
#pragma unroll
    for (int m = 1; m <= 32; m <<= 1) lmax = fmaxf(lmax, __shfl_xor(lmax, m, 64));
    if (lane == 0) redm[wave] = lmax;

    const float ib0 = bcast[0], ib1 = bcast[1], ib2 = bcast[2], ib3 = bcast[3], ib4 = bcast[4];
    float qsum = 0.0f;
#pragma unroll
    for (int k = 0; k < 4; ++k) {
      float v = l2r[k];
      qsum += __expf(-v * ib0) + __expf(-v * ib1) + __expf(-v * ib2) +
              __expf(-v * ib3) + __expf(-v * ib4);
    }
    // lanes with bit4=0: col-half X; bit4=1: col-half Y
    qsum += __shfl_xor(qsum, 1, 64);
    qsum += __shfl_xor(qsum, 2, 64);
    qsum += __shfl_xor(qsum, 4, 64);
    qsum += __shfl_xor(qsum, 8, 64);
    qsum += __shfl_xor(qsum, 32, 64);
    if (lane == 0) atomicAdd(&quad2[0], qsum);   // LDS atomic, cols X
    if (lane == 16) atomicAdd(&quad2[1], qsum);  // LDS atomic, cols Y
    __syncthreads();

    if (tid == 0) {
      float mx = 0.0f;
      for (int w = 0; w < 16; ++w) mx = fmaxf(mx, redm[w]);
      float4* part = (float4*)(ws + PART_OFF);
      part[b] = make_float4(quad2[0], quad2[1], mx, 0.0f);
    }
  }

  __threadfence();
  grid.sync();  // all part[] visible

  // ================= PHASE 3: block 0 combines all partials =================
  if (b == 0) {
    float xx = 0.f, xy = 0.f, yx = 0.f, yy = 0.f, mx = 0.f;
    if (tid < NBLK) {
      const float4* part = (const float4*)(ws + PART_OFF);
      float4 pt = part[tid];
      int rbq = tid & 3;
      if (rbq < 2) { xx = pt.x; xy = pt.y; }
      else         { yx = pt.x; yy = pt.y; }
      if ((tid >> 2) == NSPLIT - 1) mx = pt.z;
    }
#pragma unroll
    for (int m = 1; m <= 32; m <<= 1) {
      xx += __shfl_xor(xx, m, 64);
      xy += __shfl_xor(xy, m, 64);
      yx += __shfl_xor(yx, m, 64);
      yy += __shfl_xor(yy, m, 64);
      mx = fmaxf(mx, __shfl_xor(mx, m, 64));
    }
    if (lane == 0 && wave < 4) {
      fr[wave][0] = xx; fr[wave][1] = xy; fr[wave][2] = yx; fr[wave][3] = yy; fr[wave][4] = mx;
    }
    __syncthreads();
    if (tid == 0) {
      float sxx = 0, sxy = 0, syx = 0, syy = 0, smx = 0;
      for (int w = 0; w < 4; ++w) {
        sxx += fr[w][0]; sxy += fr[w][1]; syx += fr[w][2]; syy += fr[w][3];
        smx = fmaxf(smx, fr[w][4]);
      }
      const float inv = 1.0f / (4096.0f * 64.0f);  // /(64*64) then /P
      out[0] = (sxx + syy - sxy - syx) * inv;
      out[1] = smx;
      out[2] = sxx * inv;
      out[3] = syy * inv;
      out[4] = sxy * inv;
      out[5] = syx * inv;
    }
  }
}

extern "C" void kernel_launch(void* const* d_in, const int* in_sizes, int n_in,
                              void* d_out, int out_size, void* d_ws, size_t ws_size,
                              hipStream_t stream) {
  const float* src = (const float*)d_in[0];
  const float* tgt = (const float*)d_in[1];
  float* out = (float*)d_out;
  float* ws = (float*)d_ws;  // slabs 16.8 MB + gsum + partials
  void* args[] = {(void*)&src, (void*)&tgt, (void*)&ws, (void*)&out};
  hipLaunchCooperativeKernel((const void*)mmd_fused, dim3(NBLK), dim3(1024), args, 0,
                             stream);
}

// Round 10
// 295.093 us; speedup vs baseline: 1.0320x; 1.0320x over previous
//
#include <hip/hip_runtime.h>

typedef _Float16 half8 __attribute__((ext_vector_type(8)));
typedef float floatx4 __attribute__((ext_vector_type(4)));
typedef unsigned int uint2v __attribute__((ext_vector_type(2)));

#define NSPLIT 64
#define KS 64
#define DIM 2048
#define NROW 128            // 2*KS rows of T per split
#define BK 128              // k-panel width
#define KSPL 4              // k-chunks per split -> 256 blocks
#define KCH (DIM / KSPL)    // 512
#define NKC_A (KCH / BK)    // 4 panels per block
#define SST 152             // stage row stride (fp16): 304 B, 16B-aligned, 2-way banks (free)
#define GSZ (NROW * NROW)   // 16384 floats per partial-gram slab
#define NBLK (NSPLIT * KSPL)          // 256 blocks
#define GT2_OFF (NBLK * GSZ)          // per-block sum-of-gram scalars (256 floats)
#define PART_OFF (GT2_OFF + NBLK)     // per-split partials (64 x float4 = 256 floats)
#define MX_OFF (PART_OFF + 256)       // max_l2 of last split (1 float)
#define FLAG_OFF (MX_OFF + 1)         // int region: 64 split flags + 1 done counter

// Slab layout fragment-major: float index = wave*1024 + acc*256 + lane*4 + reg
// wave = (row>>5)*4 + (col>>5); acc = ((row>>4)&1)*2 + ((col>>4)&1);
// lane = ((row&15)>>2)*16 + (col&15); reg = row&3.

__device__ __forceinline__ unsigned int pk16(float a, float b) {
  return __builtin_bit_cast(unsigned int, __builtin_amdgcn_cvt_pkrtz(a, b));
}

__global__ __launch_bounds__(1024) void mmd_fused(const float* __restrict__ src,
                                                  const float* __restrict__ tgt,
                                                  float* __restrict__ ws,
                                                  float* __restrict__ out) {
  __shared__ __align__(16) _Float16 stage[NROW * SST];  // ~38 KB
  __shared__ float red[16];
  __shared__ float sqv[NROW];
  __shared__ float bcast[8];
  __shared__ float redm[16];
  __shared__ float quad4[4];
  __shared__ int sh_go;

  const int b = blockIdx.x;
  const int p = b >> 2;
  const int c = b & (KSPL - 1);
  const int tid = threadIdx.x;
  const int lane = tid & 63;
  const int wave = tid >> 6;
  int* iflag = (int*)(ws + FLAG_OFF);

  // ================= PHASE 1: partial gram (identical math to R7) =================
  {
    const int srow = tid >> 3;
    const int c4 = (tid & 7) * 4;
    const float* rowp = ((srow < KS) ? (src + (size_t)(p * KS + srow) * DIM)
                                     : (tgt + (size_t)(p * KS + (srow - KS)) * DIM)) +
                        c * KCH;

    const int wr = (wave >> 2) * 32;
    const int wc = (wave & 3) * 32;
    const int frr = lane & 15;
    const int fk = (lane >> 4) * 8;

    floatx4 acc00 = {0.f, 0.f, 0.f, 0.f};
    floatx4 acc01 = {0.f, 0.f, 0.f, 0.f};
    floatx4 acc10 = {0.f, 0.f, 0.f, 0.f};
    floatx4 acc11 = {0.f, 0.f, 0.f, 0.f};

    float4 f0, f1, f2, f3;
#define LOADK(kc)                                      \
    do {                                               \
      const float* gp_ = rowp + (kc) * BK + c4;        \
      f0 = *(const float4*)(gp_);                      \
      f1 = *(const float4*)(gp_ + 32);                 \
      f2 = *(const float4*)(gp_ + 64);                 \
      f3 = *(const float4*)(gp_ + 96);                 \
    } while (0)

    LOADK(0);
    for (int kc = 0; kc < NKC_A; ++kc) {
      __syncthreads();
      {
        _Float16* sp = &stage[srow * SST + c4];
        *(uint2v*)(sp)      = (uint2v){pk16(f0.x, f0.y), pk16(f0.z, f0.w)};
        *(uint2v*)(sp + 32) = (uint2v){pk16(f1.x, f1.y), pk16(f1.z, f1.w)};
        *(uint2v*)(sp + 64) = (uint2v){pk16(f2.x, f2.y), pk16(f2.z, f2.w)};
        *(uint2v*)(sp + 96) = (uint2v){pk16(f3.x, f3.y), pk16(f3.z, f3.w)};
      }
      __syncthreads();
      if (kc + 1 < NKC_A) LOADK(kc + 1);  // prefetch next panel under MFMA
#pragma unroll
      for (int ks = 0; ks < 4; ++ks) {
        const int ko = ks * 32 + fk;
        half8 a0 = *(const half8*)&stage[(wr + frr) * SST + ko];
        half8 a1 = *(const half8*)&stage[(wr + 16 + frr) * SST + ko];
        half8 b0 = *(const half8*)&stage[(wc + frr) * SST + ko];
        half8 b1 = *(const half8*)&stage[(wc + 16 + frr) * SST + ko];
        acc00 = __builtin_amdgcn_mfma_f32_16x16x32_f16(a0, b0, acc00, 0, 0, 0);
        acc01 = __builtin_amdgcn_mfma_f32_16x16x32_f16(a0, b1, acc01, 0, 0, 0);
        acc10 = __builtin_amdgcn_mfma_f32_16x16x32_f16(a1, b0, acc10, 0, 0, 0);
        acc11 = __builtin_amdgcn_mfma_f32_16x16x32_f16(a1, b1, acc11, 0, 0, 0);
      }
    }
#undef LOADK

    // fragment-major slab store: contiguous dwordx4, no transpose
    float* wsp = ws + (size_t)b * GSZ + wave * 1024 + lane * 4;
    *(floatx4*)(wsp)       = acc00;
    *(floatx4*)(wsp + 256) = acc01;
    *(floatx4*)(wsp + 512) = acc10;
    *(floatx4*)(wsp + 768) = acc11;

    float gsum = 0.0f;
#pragma unroll
    for (int r = 0; r < 4; ++r) gsum += acc00[r] + acc01[r] + acc10[r] + acc11[r];
#pragma unroll
    for (int m = 1; m <= 32; m <<= 1) gsum += __shfl_xor(gsum, m, 64);
    if (lane == 0) red[wave] = gsum;
    __syncthreads();
    if (tid == 0) ws[GT2_OFF + b] = red[0] + red[1] + red[2] + red[3] + red[4] + red[5] +
                                    red[6] + red[7] + red[8] + red[9] + red[10] + red[11] +
                                    red[12] + red[13] + red[14] + red[15];
  }

  // ---- release our slab+gsum, then "last sibling does the reduce" (no spinning)
  __syncthreads();
  __threadfence();
  if (tid == 0) {
    int prev = __hip_atomic_fetch_add(&iflag[p], 1, __ATOMIC_ACQ_REL,
                                      __HIP_MEMORY_SCOPE_AGENT);
    sh_go = (prev == KSPL - 1) ? 1 : 0;
  }
  __syncthreads();
  if (!sh_go) return;   // 3 of 4 sibling blocks exit here
  __threadfence();      // acquire: see sibling slabs

  // ================= PHASE 2: full-split reduce (rb = 0..3) =================
  {
    const float* sb = ws + (size_t)(p * KSPL) * GSZ;
    const int cg2 = tid & 31;  // cols cg2*4 .. cg2*4+3

    if (tid < NROW) {  // diagonal, same slab order as strips -> exact l2_ii = 0
      const int i = tid;
      const int wd = (i >> 5) * 5;
      const int ad = ((i >> 4) & 1) * 3;
      const int lnd = (((i & 15) >> 2) << 4) + (i & 15);
      const int idxd = wd * 1024 + ad * 256 + lnd * 4 + (i & 3);
      float d = 0.0f;
#pragma unroll
      for (int c8 = 0; c8 < KSPL; ++c8) d += sb[(size_t)c8 * GSZ + idxd];
      sqv[i] = d;
    }
    if (tid < 4) quad4[tid] = 0.0f;
    __syncthreads();

    if (tid == 0) {
      float ssq = 0.0f;
      for (int i = 0; i < NROW; ++i) ssq += sqv[i];
      float gt = ws[GT2_OFF + p * 4 + 0] + ws[GT2_OFF + p * 4 + 1] +
                 ws[GT2_OFF + p * 4 + 2] + ws[GT2_OFF + p * 4 + 3];
      float suml2 = 2.0f * (float)NROW * ssq - 2.0f * gt;       // sum(l2) identity
      float bwv = suml2 / (float)(NROW * NROW - NROW) * 0.25f;  // /(n^2-n) /KERNEL_MUL^2
      float mult = 1.0f;
      for (int k = 0; k < 5; ++k) {
        bcast[k] = 1.0f / (bwv * mult + 1e-9f);
        mult *= 2.0f;
      }
    }
    __syncthreads();

    const float ib0 = bcast[0], ib1 = bcast[1], ib2 = bcast[2], ib3 = bcast[3], ib4 = bcast[4];
    float lmax = 0.0f;

#pragma unroll
    for (int rb = 0; rb < 4; ++rb) {
      const int row = rb * 32 + (tid >> 5);
      const int wv = ((row >> 5) << 2) + (cg2 >> 3);
      const int a = (((row >> 4) & 1) << 1) + ((cg2 >> 2) & 1);
      const int ln = (((row & 15) >> 2) << 4) + ((cg2 & 3) << 2);
      const int idx = wv * 1024 + a * 256 + ln * 4 + (row & 3);

      float g0 = 0.f, g1 = 0.f, g2 = 0.f, g3 = 0.f;
#pragma unroll
      for (int c8 = 0; c8 < KSPL; ++c8) {
        const float* bp = sb + (size_t)c8 * GSZ + idx;
        g0 += bp[0]; g1 += bp[4]; g2 += bp[8]; g3 += bp[12];
      }

      const float sqi = sqv[row];
      const float gg[4] = {g0, g1, g2, g3};
      float qsum = 0.0f;
#pragma unroll
      for (int k = 0; k < 4; ++k) {
        float v = sqi + sqv[cg2 * 4 + k] - 2.0f * gg[k];
        lmax = fmaxf(lmax, v);
        qsum += __expf(-v * ib0) + __expf(-v * ib1) + __expf(-v * ib2) +
                __expf(-v * ib3) + __expf(-v * ib4);
      }
      // reduce over lane bits 0,1,2,3,5 — leaves bit4 = col-half
      qsum += __shfl_xor(qsum, 1, 64);
      qsum += __shfl_xor(qsum, 2, 64);
      qsum += __shfl_xor(qsum, 4, 64);
      qsum += __shfl_xor(qsum, 8, 64);
      qsum += __shfl_xor(qsum, 32, 64);
      const int rhalf = (rb >= 2) ? 2 : 0;  // row-half
      if (lane == 0) atomicAdd(&quad4[rhalf + 0], qsum);   // cols X
      if (lane == 16) atomicAdd(&quad4[rhalf + 1], qsum);  // cols Y
    }

    // block max of lmax (only consumed for p == 63)
#pragma unroll
    for (int m = 1; m <= 32; m <<= 1) lmax = fmaxf(lmax, __shfl_xor(lmax, m, 64));
    if (lane == 0) redm[wave] = lmax;
    __syncthreads();

    if (tid == 0) {
      if (p == NSPLIT - 1) {
        float mx = 0.0f;
        for (int w = 0; w < 16; ++w) mx = fmaxf(mx, redm[w]);
        ws[MX_OFF] = mx;
      }
      // quad4: [XX, XY, YX, YY] sums for this split
      float4* part = (float4*)(ws + PART_OFF);
      part[p] = make_float4(quad4[0], quad4[1], quad4[2], quad4[3]);
    }
  }

  // ---- release partials, then "last split does the final combine"
  __syncthreads();
  __threadfence();
  if (tid == 0) {
    int prev = __hip_atomic_fetch_add(&iflag[NSPLIT], 1, __ATOMIC_ACQ_REL,
                                      __HIP_MEMORY_SCOPE_AGENT);
    sh_go = (prev == NSPLIT - 1) ? 1 : 0;
  }
  __syncthreads();
  if (!sh_go) return;   // 63 of 64 split-reducers exit here
  __threadfence();      // acquire: see all part[] + MX

  // ================= PHASE 3: final combine (one wave) =================
  if (wave == 0) {
    float xx = 0.f, xy = 0.f, yx = 0.f, yy = 0.f;
    if (lane < NSPLIT) {
      const float4* part = (const float4*)(ws + PART_OFF);
      float4 pt = part[lane];
      xx = pt.x; xy = pt.y; yx = pt.z; yy = pt.w;
    }
#pragma unroll
    for (int m = 1; m <= 32; m <<= 1) {
      xx += __shfl_xor(xx, m, 64);
      xy += __shfl_xor(xy, m, 64);
      yx += __shfl_xor(yx, m, 64);
      yy += __shfl_xor(yy, m, 64);
    }
    if (lane == 0) {
      const float inv = 1.0f / (4096.0f * 64.0f);  // /(64*64) then /P
      out[0] = (xx + yy - xy - yx) * inv;
      out[1] = ws[MX_OFF];
      out[2] = xx * inv;
      out[3] = yy * inv;
      out[4] = xy * inv;
      out[5] = yx * inv;
    }
  }
}

extern "C" void kernel_launch(void* const* d_in, const int* in_sizes, int n_in,
                              void* d_out, int out_size, void* d_ws, size_t ws_size,
                              hipStream_t stream) {
  const float* src = (const float*)d_in[0];
  const float* tgt = (const float*)d_in[1];
  float* out = (float*)d_out;
  float* ws = (float*)d_ws;  // slabs 16.8 MB + gsum + partials + mx + flags
  // zero the 64 split flags + 1 done counter (async, graph-capture-legal)
  hipMemsetAsync(ws + FLAG_OFF, 0, (NSPLIT + 1) * sizeof(int), stream);
  mmd_fused<<<NBLK, 1024, 0, stream>>>(src, tgt, ws, out);
}

// Round 11
// 139.763 us; speedup vs baseline: 2.1789x; 2.1114x over previous
//
#include <hip/hip_runtime.h>

typedef _Float16 half8 __attribute__((ext_vector_type(8)));
typedef float floatx4 __attribute__((ext_vector_type(4)));
typedef unsigned int uint2v __attribute__((ext_vector_type(2)));

#define NSPLIT 64
#define KS 64
#define DIM 2048
#define NROW 128            // 2*KS rows of T per split
#define BK 128              // k-panel width
#define KSPL 4              // k-chunks per split -> 256 blocks
#define KCH (DIM / KSPL)    // 512
#define NKC_A (KCH / BK)    // 4 panels per block
#define SST 152             // stage row stride (fp16): 304 B, 16B-aligned, 2-way banks (free)
#define GSZ (NROW * NROW)   // 16384 floats per partial-gram slab
#define NBLK (NSPLIT * KSPL)          // 256 blocks
#define GT2_OFF (NBLK * GSZ)          // per-block sum-of-gram scalars (256 floats)
#define PART_OFF (GT2_OFF + NBLK)     // per-split partials (64 x float4 = 256 floats)
#define MX_OFF (PART_OFF + 256)       // max_l2 of last split (1 float)
#define FLAG_OFF (MX_OFF + 1)         // int region: 64 split flags + 1 done counter

// Slab layout fragment-major: float index = wave*1024 + acc*256 + lane*4 + reg
// wave = (row>>5)*4 + (col>>5); acc = ((row>>4)&1)*2 + ((col>>4)&1);
// lane = ((row&15)>>2)*16 + (col&15); reg = row&3.

__device__ __forceinline__ unsigned int pk16(float a, float b) {
  return __builtin_bit_cast(unsigned int, __builtin_amdgcn_cvt_pkrtz(a, b));
}

__global__ __launch_bounds__(1024) void mmd_fused(const float* __restrict__ src,
                                                  const float* __restrict__ tgt,
                                                  float* __restrict__ ws,
                                                  float* __restrict__ out) {
  __shared__ __align__(16) _Float16 stage[NROW * SST];  // ~38 KB
  __shared__ float red[16];
  __shared__ float sqv[NROW];
  __shared__ float bcast[8];
  __shared__ float redm[16];
  __shared__ float quad4[4];
  __shared__ int sh_go;

  const int b = blockIdx.x;
  const int p = b >> 2;
  const int c = b & (KSPL - 1);
  const int tid = threadIdx.x;
  const int lane = tid & 63;
  const int wave = tid >> 6;
  int* iflag = (int*)(ws + FLAG_OFF);

  // ================= PHASE 1: partial gram (identical math to R7/R10) =================
  {
    const int srow = tid >> 3;
    const int c4 = (tid & 7) * 4;
    const float* rowp = ((srow < KS) ? (src + (size_t)(p * KS + srow) * DIM)
                                     : (tgt + (size_t)(p * KS + (srow - KS)) * DIM)) +
                        c * KCH;

    const int wr = (wave >> 2) * 32;
    const int wc = (wave & 3) * 32;
    const int frr = lane & 15;
    const int fk = (lane >> 4) * 8;

    floatx4 acc00 = {0.f, 0.f, 0.f, 0.f};
    floatx4 acc01 = {0.f, 0.f, 0.f, 0.f};
    floatx4 acc10 = {0.f, 0.f, 0.f, 0.f};
    floatx4 acc11 = {0.f, 0.f, 0.f, 0.f};

    float4 f0, f1, f2, f3;
#define LOADK(kc)                                      \
    do {                                               \
      const float* gp_ = rowp + (kc) * BK + c4;        \
      f0 = *(const float4*)(gp_);                      \
      f1 = *(const float4*)(gp_ + 32);                 \
      f2 = *(const float4*)(gp_ + 64);                 \
      f3 = *(const float4*)(gp_ + 96);                 \
    } while (0)

    LOADK(0);
    for (int kc = 0; kc < NKC_A; ++kc) {
      __syncthreads();
      {
        _Float16* sp = &stage[srow * SST + c4];
        *(uint2v*)(sp)      = (uint2v){pk16(f0.x, f0.y), pk16(f0.z, f0.w)};
        *(uint2v*)(sp + 32) = (uint2v){pk16(f1.x, f1.y), pk16(f1.z, f1.w)};
        *(uint2v*)(sp + 64) = (uint2v){pk16(f2.x, f2.y), pk16(f2.z, f2.w)};
        *(uint2v*)(sp + 96) = (uint2v){pk16(f3.x, f3.y), pk16(f3.z, f3.w)};
      }
      __syncthreads();
      if (kc + 1 < NKC_A) LOADK(kc + 1);  // prefetch next panel under MFMA
#pragma unroll
      for (int ks = 0; ks < 4; ++ks) {
        const int ko = ks * 32 + fk;
        half8 a0 = *(const half8*)&stage[(wr + frr) * SST + ko];
        half8 a1 = *(const half8*)&stage[(wr + 16 + frr) * SST + ko];
        half8 b0 = *(const half8*)&stage[(wc + frr) * SST + ko];
        half8 b1 = *(const half8*)&stage[(wc + 16 + frr) * SST + ko];
        acc00 = __builtin_amdgcn_mfma_f32_16x16x32_f16(a0, b0, acc00, 0, 0, 0);
        acc01 = __builtin_amdgcn_mfma_f32_16x16x32_f16(a0, b1, acc01, 0, 0, 0);
        acc10 = __builtin_amdgcn_mfma_f32_16x16x32_f16(a1, b0, acc10, 0, 0, 0);
        acc11 = __builtin_amdgcn_mfma_f32_16x16x32_f16(a1, b1, acc11, 0, 0, 0);
      }
    }
#undef LOADK

    // fragment-major slab store: contiguous dwordx4, no transpose
    float* wsp = ws + (size_t)b * GSZ + wave * 1024 + lane * 4;
    *(floatx4*)(wsp)       = acc00;
    *(floatx4*)(wsp + 256) = acc01;
    *(floatx4*)(wsp + 512) = acc10;
    *(floatx4*)(wsp + 768) = acc11;

    float gsum = 0.0f;
#pragma unroll
    for (int r = 0; r < 4; ++r) gsum += acc00[r] + acc01[r] + acc10[r] + acc11[r];
#pragma unroll
    for (int m = 1; m <= 32; m <<= 1) gsum += __shfl_xor(gsum, m, 64);
    if (lane == 0) red[wave] = gsum;
    __syncthreads();
    if (tid == 0) ws[GT2_OFF + b] = red[0] + red[1] + red[2] + red[3] + red[4] + red[5] +
                                    red[6] + red[7] + red[8] + red[9] + red[10] + red[11] +
                                    red[12] + red[13] + red[14] + red[15];
  }

  // ---- handoff: ONE fence per block, not per wave. __syncthreads drains all
  // waves' stores to the XCD L2 (vmcnt(0) before s_barrier); tid0's ACQ_REL
  // atomic then release-writes-back (wbl2) and acquire-invalidates (inv).
  __syncthreads();
  if (tid == 0) {
    int prev = __hip_atomic_fetch_add(&iflag[p], 1, __ATOMIC_ACQ_REL,
                                      __HIP_MEMORY_SCOPE_AGENT);
    sh_go = (prev == KSPL - 1) ? 1 : 0;
  }
  __syncthreads();
  if (!sh_go) return;   // 3 of 4 sibling blocks exit here

  // ================= PHASE 2: full-split reduce (rb = 0..3) =================
  {
    const float* sb = ws + (size_t)(p * KSPL) * GSZ;
    const int cg2 = tid & 31;  // cols cg2*4 .. cg2*4+3

    if (tid < NROW) {  // diagonal, same slab order as strips -> exact l2_ii = 0
      const int i = tid;
      const int wd = (i >> 5) * 5;
      const int ad = ((i >> 4) & 1) * 3;
      const int lnd = (((i & 15) >> 2) << 4) + (i & 15);
      const int idxd = wd * 1024 + ad * 256 + lnd * 4 + (i & 3);
      float d = 0.0f;
#pragma unroll
      for (int c8 = 0; c8 < KSPL; ++c8) d += sb[(size_t)c8 * GSZ + idxd];
      sqv[i] = d;
    }
    if (tid < 4) quad4[tid] = 0.0f;
    __syncthreads();

    if (tid == 0) {
      float ssq = 0.0f;
      for (int i = 0; i < NROW; ++i) ssq += sqv[i];
      float gt = ws[GT2_OFF + p * 4 + 0] + ws[GT2_OFF + p * 4 + 1] +
                 ws[GT2_OFF + p * 4 + 2] + ws[GT2_OFF + p * 4 + 3];
      float suml2 = 2.0f * (float)NROW * ssq - 2.0f * gt;       // sum(l2) identity
      float bwv = suml2 / (float)(NROW * NROW - NROW) * 0.25f;  // /(n^2-n) /KERNEL_MUL^2
      float mult = 1.0f;
      for (int k = 0; k < 5; ++k) {
        bcast[k] = 1.0f / (bwv * mult + 1e-9f);
        mult *= 2.0f;
      }
    }
    __syncthreads();

    const float ib0 = bcast[0], ib1 = bcast[1], ib2 = bcast[2], ib3 = bcast[3], ib4 = bcast[4];
    float lmax = 0.0f;

#pragma unroll
    for (int rb = 0; rb < 4; ++rb) {
      const int row = rb * 32 + (tid >> 5);
      const int wv = ((row >> 5) << 2) + (cg2 >> 3);
      const int a = (((row >> 4) & 1) << 1) + ((cg2 >> 2) & 1);
      const int ln = (((row & 15) >> 2) << 4) + ((cg2 & 3) << 2);
      const int idx = wv * 1024 + a * 256 + ln * 4 + (row & 3);

      float g0 = 0.f, g1 = 0.f, g2 = 0.f, g3 = 0.f;
#pragma unroll
      for (int c8 = 0; c8 < KSPL; ++c8) {
        const float* bp = sb + (size_t)c8 * GSZ + idx;
        g0 += bp[0]; g1 += bp[4]; g2 += bp[8]; g3 += bp[12];
      }

      const float sqi = sqv[row];
      const float gg[4] = {g0, g1, g2, g3};
      float qsum = 0.0f;
#pragma unroll
      for (int k = 0; k < 4; ++k) {
        float v = sqi + sqv[cg2 * 4 + k] - 2.0f * gg[k];
        lmax = fmaxf(lmax, v);
        qsum += __expf(-v * ib0) + __expf(-v * ib1) + __expf(-v * ib2) +
                __expf(-v * ib3) + __expf(-v * ib4);
      }
      // reduce over lane bits 0,1,2,3,5 — leaves bit4 = col-half
      qsum += __shfl_xor(qsum, 1, 64);
      qsum += __shfl_xor(qsum, 2, 64);
      qsum += __shfl_xor(qsum, 4, 64);
      qsum += __shfl_xor(qsum, 8, 64);
      qsum += __shfl_xor(qsum, 32, 64);
      const int rhalf = (rb >= 2) ? 2 : 0;  // row-half
      if (lane == 0) atomicAdd(&quad4[rhalf + 0], qsum);   // LDS atomic, cols X
      if (lane == 16) atomicAdd(&quad4[rhalf + 1], qsum);  // LDS atomic, cols Y
    }

    // block max of lmax (only consumed for p == 63)
#pragma unroll
    for (int m = 1; m <= 32; m <<= 1) lmax = fmaxf(lmax, __shfl_xor(lmax, m, 64));
    if (lane == 0) redm[wave] = lmax;
    __syncthreads();

    if (tid == 0) {
      if (p == NSPLIT - 1) {
        float mx = 0.0f;
        for (int w = 0; w < 16; ++w) mx = fmaxf(mx, redm[w]);
        ws[MX_OFF] = mx;
      }
      // quad4: [XX, XY, YX, YY] sums for this split
      float4* part = (float4*)(ws + PART_OFF);
      part[p] = make_float4(quad4[0], quad4[1], quad4[2], quad4[3]);
    }
  }

  // ---- handoff 2: same single-fence pattern on the done counter
  __syncthreads();
  if (tid == 0) {
    int prev = __hip_atomic_fetch_add(&iflag[NSPLIT], 1, __ATOMIC_ACQ_REL,
                                      __HIP_MEMORY_SCOPE_AGENT);
    sh_go = (prev == NSPLIT - 1) ? 1 : 0;
  }
  __syncthreads();
  if (!sh_go) return;   // 63 of 64 split-reducers exit here

  // ================= PHASE 3: final combine (one wave) =================
  if (wave == 0) {
    float xx = 0.f, xy = 0.f, yx = 0.f, yy = 0.f;
    if (lane < NSPLIT) {
      const float4* part = (const float4*)(ws + PART_OFF);
      float4 pt = part[lane];
      xx = pt.x; xy = pt.y; yx = pt.z; yy = pt.w;
    }
#pragma unroll
    for (int m = 1; m <= 32; m <<= 1) {
      xx += __shfl_xor(xx, m, 64);
      xy += __shfl_xor(xy, m, 64);
      yx += __shfl_xor(yx, m, 64);
      yy += __shfl_xor(yy, m, 64);
    }
    if (lane == 0) {
      const float inv = 1.0f / (4096.0f * 64.0f);  // /(64*64) then /P
      out[0] = (xx + yy - xy - yx) * inv;
      out[1] = ws[MX_OFF];
      out[2] = xx * inv;
      out[3] = yy * inv;
      out[4] = xy * inv;
      out[5] = yx * inv;
    }
  }
}

extern "C" void kernel_launch(void* const* d_in, const int* in_sizes, int n_in,
                              void* d_out, int out_size, void* d_ws, size_t ws_size,
                              hipStream_t stream) {
  const float* src = (const float*)d_in[0];
  const float* tgt = (const float*)d_in[1];
  float* out = (float*)d_out;
  float* ws = (float*)d_ws;  // slabs 16.8 MB + gsum + partials + mx + flags
  // zero the 64 split flags + 1 done counter (async, graph-capture-legal)
  hipMemsetAsync(ws + FLAG_OFF, 0, (NSPLIT + 1) * sizeof(int), stream);
  mmd_fused<<<NBLK, 1024, 0, stream>>>(src, tgt, ws, out);
}

// Round 12
// 112.540 us; speedup vs baseline: 2.7059x; 1.2419x over previous
//
#include <hip/hip_runtime.h>

typedef _Float16 half8 __attribute__((ext_vector_type(8)));
typedef _Float16 half4v __attribute__((ext_vector_type(4)));
typedef float floatx4 __attribute__((ext_vector_type(4)));
typedef unsigned int uint2v __attribute__((ext_vector_type(2)));

#define NSPLIT 64
#define KS 64
#define DIM 2048
#define NROW 128            // 2*KS rows of T per split
#define BK 128              // k-panel width
#define KSPL 4              // k-chunks per split -> 256 blocks
#define KCH (DIM / KSPL)    // 512
#define NKC_A (KCH / BK)    // 4 panels per block
#define SST 152             // stage row stride (fp16): 304 B, 16B-aligned, 2-way banks (free)
#define GSZ (NROW * NROW)   // 16384 halfs per partial-gram slab (fp16 now)
#define NBLK (NSPLIT * KSPL)            // 256 blocks
// float-index offsets into ws (slabs are halfs: NBLK*GSZ*2 B = NBLK*GSZ/2 floats)
#define GT2F_OFF (NBLK * GSZ / 2)       // per-block sum-of-gram scalars (256 floats)
#define PART_OFF (GT2F_OFF + NBLK)      // per-reduce-block partials (256 x float4)
#define FLAG_OFF (PART_OFF + NBLK * 4)  // 1 int done-counter

// Slab layout fragment-major (half index): idx = wave*1024 + acc*256 + lane*4 + reg
// wave = (row>>5)*4 + (col>>5); acc = ((row>>4)&1)*2 + ((col>>4)&1);
// lane = ((row&15)>>2)*16 + (col&15); reg = row&3.

__device__ __forceinline__ unsigned int pk16(float a, float b) {
  return __builtin_bit_cast(unsigned int, __builtin_amdgcn_cvt_pkrtz(a, b));
}

// ---- Kernel A: partial gram over one 512-wide k-chunk. grid = 256. (R7 core)
__global__ __launch_bounds__(1024) void gram_kernel(const float* __restrict__ src,
                                                    const float* __restrict__ tgt,
                                                    float* __restrict__ ws) {
  __shared__ __align__(16) _Float16 stage[NROW * SST];  // ~38 KB
  __shared__ float red[16];

  const int p = blockIdx.x >> 2;
  const int c = blockIdx.x & (KSPL - 1);
  const int tid = threadIdx.x;
  const int lane = tid & 63;
  const int wave = tid >> 6;

  const int srow = tid >> 3;
  const int c4 = (tid & 7) * 4;
  const float* rowp = ((srow < KS) ? (src + (size_t)(p * KS + srow) * DIM)
                                   : (tgt + (size_t)(p * KS + (srow - KS)) * DIM)) +
                      c * KCH;

  const int wr = (wave >> 2) * 32;
  const int wc = (wave & 3) * 32;
  const int fr = lane & 15;
  const int fk = (lane >> 4) * 8;

  floatx4 acc00 = {0.f, 0.f, 0.f, 0.f};
  floatx4 acc01 = {0.f, 0.f, 0.f, 0.f};
  floatx4 acc10 = {0.f, 0.f, 0.f, 0.f};
  floatx4 acc11 = {0.f, 0.f, 0.f, 0.f};

  float4 f0, f1, f2, f3;
#define LOADK(kc)                                      \
  do {                                                 \
    const float* gp_ = rowp + (kc) * BK + c4;          \
    f0 = *(const float4*)(gp_);                        \
    f1 = *(const float4*)(gp_ + 32);                   \
    f2 = *(const float4*)(gp_ + 64);                   \
    f3 = *(const float4*)(gp_ + 96);                   \
  } while (0)

  LOADK(0);
  for (int kc = 0; kc < NKC_A; ++kc) {
    __syncthreads();  // previous panel's LDS reads done before overwrite
    {
      _Float16* sp = &stage[srow * SST + c4];
      *(uint2v*)(sp)      = (uint2v){pk16(f0.x, f0.y), pk16(f0.z, f0.w)};
      *(uint2v*)(sp + 32) = (uint2v){pk16(f1.x, f1.y), pk16(f1.z, f1.w)};
      *(uint2v*)(sp + 64) = (uint2v){pk16(f2.x, f2.y), pk16(f2.z, f2.w)};
      *(uint2v*)(sp + 96) = (uint2v){pk16(f3.x, f3.y), pk16(f3.z, f3.w)};
    }
    __syncthreads();
    if (kc + 1 < NKC_A) LOADK(kc + 1);  // prefetch next panel under MFMA
#pragma unroll
    for (int ks = 0; ks < 4; ++ks) {
      const int ko = ks * 32 + fk;
      half8 a0 = *(const half8*)&stage[(wr + fr) * SST + ko];
      half8 a1 = *(const half8*)&stage[(wr + 16 + fr) * SST + ko];
      half8 b0 = *(const half8*)&stage[(wc + fr) * SST + ko];
      half8 b1 = *(const half8*)&stage[(wc + 16 + fr) * SST + ko];
      acc00 = __builtin_amdgcn_mfma_f32_16x16x32_f16(a0, b0, acc00, 0, 0, 0);
      acc01 = __builtin_amdgcn_mfma_f32_16x16x32_f16(a0, b1, acc01, 0, 0, 0);
      acc10 = __builtin_amdgcn_mfma_f32_16x16x32_f16(a1, b0, acc10, 0, 0, 0);
      acc11 = __builtin_amdgcn_mfma_f32_16x16x32_f16(a1, b1, acc11, 0, 0, 0);
    }
  }
#undef LOADK

  // fp16 fragment-major slab store: 4x contiguous 512B/wave stores (RNE casts)
  _Float16* hs = (_Float16*)ws + (size_t)blockIdx.x * GSZ + wave * 1024 + lane * 4;
  {
    half4v h0, h1, h2, h3;
#pragma unroll
    for (int r = 0; r < 4; ++r) {
      h0[r] = (_Float16)acc00[r];
      h1[r] = (_Float16)acc01[r];
      h2[r] = (_Float16)acc10[r];
      h3[r] = (_Float16)acc11[r];
    }
    *(half4v*)(hs)       = h0;
    *(half4v*)(hs + 256) = h1;
    *(half4v*)(hs + 512) = h2;
    *(half4v*)(hs + 768) = h3;
  }

  // block-reduce fp32 sum of this partial gram -> ws[GT2F_OFF + b]
  float gsum = 0.0f;
#pragma unroll
  for (int r = 0; r < 4; ++r) gsum += acc00[r] + acc01[r] + acc10[r] + acc11[r];
#pragma unroll
  for (int m = 1; m <= 32; m <<= 1) gsum += __shfl_xor(gsum, m, 64);
  if (lane == 0) red[wave] = gsum;
  __syncthreads();
  if (tid == 0) {
    float t = 0.0f;
    for (int w = 0; w < 16; ++w) t += red[w];
    ws[GT2F_OFF + blockIdx.x] = t;
  }
}

// ---- Kernel B: 4 blocks per split (32 rows each), grid = 256; last-done block
//      also performs the final combine (done-counter handoff, no parallelism loss).
__global__ __launch_bounds__(1024) void reduce_kernel(float* __restrict__ ws,
                                                      float* __restrict__ out) {
  __shared__ float sqv[NROW];
  __shared__ float bcast[8];
  __shared__ float redm[16];
  __shared__ float quad2[2];
  __shared__ float fr2[4][5];
  __shared__ int sh_go;

  const int b = blockIdx.x;
  const int p = b >> 2;
  const int rb = b & 3;
  const int tid = threadIdx.x;
  const int lane = tid & 63;
  const int wave = tid >> 6;
  int* iflag = (int*)(ws + FLAG_OFF);

  const int row = rb * 32 + (tid >> 5);
  const int cg = tid & 31;  // cols cg*4 .. cg*4+3

  const _Float16* sb = (const _Float16*)ws + (size_t)(p * KSPL) * GSZ;
  // fragment-major half-index of (row, cg*4)
  const int wv = ((row >> 5) << 2) + (cg >> 3);
  const int a = (((row >> 4) & 1) << 1) + ((cg >> 2) & 1);
  const int ln = (((row & 15) >> 2) << 4) + ((cg & 3) << 2);
  const int idx = wv * 1024 + a * 256 + ln * 4 + (row & 3);

  float g0 = 0.f, g1 = 0.f, g2 = 0.f, g3 = 0.f;
#pragma unroll
  for (int c8 = 0; c8 < KSPL; ++c8) {
    const _Float16* bp = sb + (size_t)c8 * GSZ + idx;
    g0 += (float)bp[0]; g1 += (float)bp[4]; g2 += (float)bp[8]; g3 += (float)bp[12];
  }

  // diagonal (sq): same fp16 values + same sum order as strips -> l2_ii exactly 0
  if (tid < NROW) {
    const int i = tid;
    const int wd = (i >> 5) * 5;
    const int ad = ((i >> 4) & 1) * 3;
    const int lnd = (((i & 15) >> 2) << 4) + (i & 15);
    const int idxd = wd * 1024 + ad * 256 + lnd * 4 + (i & 3);
    float d = 0.0f;
#pragma unroll
    for (int c8 = 0; c8 < KSPL; ++c8) d += (float)sb[(size_t)c8 * GSZ + idxd];
    sqv[i] = d;
  }
  if (tid < 2) quad2[tid] = 0.0f;
  __syncthreads();

  if (tid == 0) {
    float ssq = 0.0f;
    for (int i = 0; i < NROW; ++i) ssq += sqv[i];
    float gt = ws[GT2F_OFF + p * 4 + 0] + ws[GT2F_OFF + p * 4 + 1] +
               ws[GT2F_OFF + p * 4 + 2] + ws[GT2F_OFF + p * 4 + 3];
    float suml2 = 2.0f * (float)NROW * ssq - 2.0f * gt;      // sum(l2) identity
    float bw = suml2 / (float)(NROW * NROW - NROW) * 0.25f;  // /(n^2-n) /KERNEL_MUL^2
    float mult = 1.0f;
    for (int k = 0; k < 5; ++k) {
      bcast[k] = 1.0f / (bw * mult + 1e-9f);
      mult *= 2.0f;
    }
  }
  __syncthreads();

  const float sqi = sqv[row];
  float l2r[4];
  float lmax = 0.0f;
  {
    const float gg[4] = {g0, g1, g2, g3};
#pragma unroll
    for (int k = 0; k < 4; ++k) {
      float v = sqi + sqv[cg * 4 + k] - 2.0f * gg[k];
      l2r[k] = v;
      lmax = fmaxf(lmax, v);
    }
  }
#pragma unroll
  for (int m = 1; m <= 32; m <<= 1) lmax = fmaxf(lmax, __shfl_xor(lmax, m, 64));
  if (lane == 0) redm[wave] = lmax;

  const float ib0 = bcast[0], ib1 = bcast[1], ib2 = bcast[2], ib3 = bcast[3], ib4 = bcast[4];
  float qsum = 0.0f;
#pragma unroll
  for (int k = 0; k < 4; ++k) {
    float v = l2r[k];
    qsum += __expf(-v * ib0) + __expf(-v * ib1) + __expf(-v * ib2) +
            __expf(-v * ib3) + __expf(-v * ib4);
  }
  // lanes with bit4=0: col-half X; bit4=1: col-half Y
  qsum += __shfl_xor(qsum, 1, 64);
  qsum += __shfl_xor(qsum, 2, 64);
  qsum += __shfl_xor(qsum, 4, 64);
  qsum += __shfl_xor(qsum, 8, 64);
  qsum += __shfl_xor(qsum, 32, 64);
  if (lane == 0) atomicAdd(&quad2[0], qsum);   // LDS atomic, cols X
  if (lane == 16) atomicAdd(&quad2[1], qsum);  // LDS atomic, cols Y
  __syncthreads();

  if (tid == 0) {
    float mx = 0.0f;
    for (int w = 0; w < 16; ++w) mx = fmaxf(mx, redm[w]);
    float4* part = (float4*)(ws + PART_OFF);
    part[b] = make_float4(quad2[0], quad2[1], mx, 0.0f);
  }

  // ---- done-counter handoff: last of 256 blocks does the final combine.
  // __syncthreads drains this block's part[] store; tid0's ACQ_REL atomic is the
  // single per-block release/acquire fence (R11-validated pattern).
  __syncthreads();
  if (tid == 0) {
    int prev = __hip_atomic_fetch_add(&iflag[0], 1, __ATOMIC_ACQ_REL,
                                      __HIP_MEMORY_SCOPE_AGENT);
    sh_go = (prev == NBLK - 1) ? 1 : 0;
  }
  __syncthreads();
  if (!sh_go) return;  // 255 of 256 blocks exit

  // final combine (threads 0..255 active for loads, barriers unconditional)
  float xx = 0.f, xy = 0.f, yx = 0.f, yy = 0.f, mx = 0.f;
  if (tid < NBLK) {
    const float4* part = (const float4*)(ws + PART_OFF);
    float4 pt = part[tid];
    int rbq = tid & 3;
    if (rbq < 2) { xx = pt.x; xy = pt.y; }
    else         { yx = pt.x; yy = pt.y; }
    if ((tid >> 2) == NSPLIT - 1) mx = pt.z;
  }
#pragma unroll
  for (int m = 1; m <= 32; m <<= 1) {
    xx += __shfl_xor(xx, m, 64);
    xy += __shfl_xor(xy, m, 64);
    yx += __shfl_xor(yx, m, 64);
    yy += __shfl_xor(yy, m, 64);
    mx = fmaxf(mx, __shfl_xor(mx, m, 64));
  }
  if (lane == 0 && wave < 4) {
    fr2[wave][0] = xx; fr2[wave][1] = xy; fr2[wave][2] = yx; fr2[wave][3] = yy; fr2[wave][4] = mx;
  }
  __syncthreads();
  if (tid == 0) {
    float sxx = 0, sxy = 0, syx = 0, syy = 0, smx = 0;
    for (int w = 0; w < 4; ++w) {
      sxx += fr2[w][0]; sxy += fr2[w][1]; syx += fr2[w][2]; syy += fr2[w][3];
      smx = fmaxf(smx, fr2[w][4]);
    }
    const float inv = 1.0f / (4096.0f * 64.0f);  // /(64*64) then /P
    out[0] = (sxx + syy - sxy - syx) * inv;
    out[1] = smx;
    out[2] = sxx * inv;
    out[3] = syy * inv;
    out[4] = sxy * inv;
    out[5] = syx * inv;
  }
}

extern "C" void kernel_launch(void* const* d_in, const int* in_sizes, int n_in,
                              void* d_out, int out_size, void* d_ws, size_t ws_size,
                              hipStream_t stream) {
  const float* src = (const float*)d_in[0];
  const float* tgt = (const float*)d_in[1];
  float* out = (float*)d_out;
  float* ws = (float*)d_ws;  // fp16 slabs 8.4 MB + gsum + partials + 1 flag
  hipMemsetAsync(ws + FLAG_OFF, 0, sizeof(int), stream);  // done counter = 0
  gram_kernel<<<NBLK, 1024, 0, stream>>>(src, tgt, ws);
  reduce_kernel<<<NBLK, 1024, 0, stream>>>(ws, out);
}

// Round 13
// 107.786 us; speedup vs baseline: 2.8253x; 1.0441x over previous
//
#include <hip/hip_runtime.h>

typedef _Float16 half8 __attribute__((ext_vector_type(8)));
typedef _Float16 half4v __attribute__((ext_vector_type(4)));
typedef float floatx4 __attribute__((ext_vector_type(4)));
typedef unsigned int uint2v __attribute__((ext_vector_type(2)));

#define NSPLIT 64
#define KS 64
#define DIM 2048
#define NROW 128            // 2*KS rows of T per split
#define BK 128              // k-panel width
#define KSPL 4              // k-chunks per split -> 256 blocks
#define KCH (DIM / KSPL)    // 512
#define NKC_A (KCH / BK)    // 4 panels per block
#define SST 152             // stage row stride (fp16): 304 B, 16B-aligned, 2-way banks (free)
#define GSZ (NROW * NROW)   // 16384 halfs per partial-gram slab (fp16)
#define NBLK (NSPLIT * KSPL)            // 256 blocks
// float-index offsets into ws (slabs are halfs: NBLK*GSZ/2 floats)
#define GT2F_OFF (NBLK * GSZ / 2)       // per-block sum-of-gram scalars (256 floats)
#define PART_OFF (GT2F_OFF + NBLK)      // per-reduce-block partials (256 x float4)

// Slab layout fragment-major (half index): idx = wave*1024 + acc*256 + lane*4 + reg
// wave = (row>>5)*4 + (col>>5); acc = ((row>>4)&1)*2 + ((col>>4)&1);
// lane = ((row&15)>>2)*16 + (col&15); reg = row&3.

__device__ __forceinline__ unsigned int pk16(float a, float b) {
  return __builtin_bit_cast(unsigned int, __builtin_amdgcn_cvt_pkrtz(a, b));
}

// ---- Kernel A: partial gram over one 512-wide k-chunk. grid = 256.
// Double-buffered LDS staging: ONE barrier per panel; loads for panel k+1 are
// in flight across the barrier and panel-k MFMA. No atomics, no fences.
__global__ __launch_bounds__(1024) void gram_kernel(const float* __restrict__ src,
                                                    const float* __restrict__ tgt,
                                                    float* __restrict__ ws) {
  __shared__ __align__(16) _Float16 stage[2][NROW * SST];  // 2 x ~38 KB
  __shared__ float red[16];

  const int p = blockIdx.x >> 2;
  const int c = blockIdx.x & (KSPL - 1);
  const int tid = threadIdx.x;
  const int lane = tid & 63;
  const int wave = tid >> 6;

  const int srow = tid >> 3;
  const int c4 = (tid & 7) * 4;
  const float* rowp = ((srow < KS) ? (src + (size_t)(p * KS + srow) * DIM)
                                   : (tgt + (size_t)(p * KS + (srow - KS)) * DIM)) +
                      c * KCH;

  const int wr = (wave >> 2) * 32;
  const int wc = (wave & 3) * 32;
  const int fr = lane & 15;
  const int fk = (lane >> 4) * 8;

  floatx4 acc00 = {0.f, 0.f, 0.f, 0.f};
  floatx4 acc01 = {0.f, 0.f, 0.f, 0.f};
  floatx4 acc10 = {0.f, 0.f, 0.f, 0.f};
  floatx4 acc11 = {0.f, 0.f, 0.f, 0.f};

  float4 f0, f1, f2, f3;
#define LOADK(kc)                                      \
  do {                                                 \
    const float* gp_ = rowp + (kc) * BK + c4;          \
    f0 = *(const float4*)(gp_);                        \
    f1 = *(const float4*)(gp_ + 32);                   \
    f2 = *(const float4*)(gp_ + 64);                   \
    f3 = *(const float4*)(gp_ + 96);                   \
  } while (0)

  LOADK(0);
#pragma unroll
  for (int kc = 0; kc < NKC_A; ++kc) {
    // convert + store panel kc into buf[kc&1] (waits on its loads only)
    {
      _Float16* sp = &stage[kc & 1][srow * SST + c4];
      *(uint2v*)(sp)      = (uint2v){pk16(f0.x, f0.y), pk16(f0.z, f0.w)};
      *(uint2v*)(sp + 32) = (uint2v){pk16(f1.x, f1.y), pk16(f1.z, f1.w)};
      *(uint2v*)(sp + 64) = (uint2v){pk16(f2.x, f2.y), pk16(f2.z, f2.w)};
      *(uint2v*)(sp + 96) = (uint2v){pk16(f3.x, f3.y), pk16(f3.z, f3.w)};
    }
    if (kc + 1 < NKC_A) LOADK(kc + 1);  // issue next panel's loads pre-barrier
    __syncthreads();                    // buf[kc&1] complete for all waves
    // safety: storing buf[(kc+2)&1] requires passing barrier kc+1, and per-wave
    // program order (MFMA kc precedes store kc+1) => all reads of buf[kc&1] done.
    const _Float16* sbuf = stage[kc & 1];
#pragma unroll
    for (int ks = 0; ks < 4; ++ks) {
      const int ko = ks * 32 + fk;
      half8 a0 = *(const half8*)&sbuf[(wr + fr) * SST + ko];
      half8 a1 = *(const half8*)&sbuf[(wr + 16 + fr) * SST + ko];
      half8 b0 = *(const half8*)&sbuf[(wc + fr) * SST + ko];
      half8 b1 = *(const half8*)&sbuf[(wc + 16 + fr) * SST + ko];
      acc00 = __builtin_amdgcn_mfma_f32_16x16x32_f16(a0, b0, acc00, 0, 0, 0);
      acc01 = __builtin_amdgcn_mfma_f32_16x16x32_f16(a0, b1, acc01, 0, 0, 0);
      acc10 = __builtin_amdgcn_mfma_f32_16x16x32_f16(a1, b0, acc10, 0, 0, 0);
      acc11 = __builtin_amdgcn_mfma_f32_16x16x32_f16(a1, b1, acc11, 0, 0, 0);
    }
  }
#undef LOADK

  // fp16 fragment-major slab store: 4x contiguous 512B/wave stores (RNE casts)
  _Float16* hs = (_Float16*)ws + (size_t)blockIdx.x * GSZ + wave * 1024 + lane * 4;
  {
    half4v h0, h1, h2, h3;
#pragma unroll
    for (int r = 0; r < 4; ++r) {
      h0[r] = (_Float16)acc00[r];
      h1[r] = (_Float16)acc01[r];
      h2[r] = (_Float16)acc10[r];
      h3[r] = (_Float16)acc11[r];
    }
    *(half4v*)(hs)       = h0;
    *(half4v*)(hs + 256) = h1;
    *(half4v*)(hs + 512) = h2;
    *(half4v*)(hs + 768) = h3;
  }

  // block-reduce fp32 sum of this partial gram -> ws[GT2F_OFF + b]
  float gsum = 0.0f;
#pragma unroll
  for (int r = 0; r < 4; ++r) gsum += acc00[r] + acc01[r] + acc10[r] + acc11[r];
#pragma unroll
  for (int m = 1; m <= 32; m <<= 1) gsum += __shfl_xor(gsum, m, 64);
  if (lane == 0) red[wave] = gsum;
  __syncthreads();
  if (tid == 0) {
    float t = 0.0f;
    for (int w = 0; w < 16; ++w) t += red[w];
    ws[GT2F_OFF + blockIdx.x] = t;
  }
}

// ---- Kernel B: 4 blocks per split (32 rows each). grid = 256. No global atomics.
__global__ __launch_bounds__(1024) void reduce_kernel(const float* __restrict__ ws,
                                                      float* __restrict__ out) {
  __shared__ float sqv[NROW];
  __shared__ float bcast[8];
  __shared__ float redm[16];
  __shared__ float quad2[2];

  const int b = blockIdx.x;
  const int p = b >> 2;
  const int rb = b & 3;
  const int tid = threadIdx.x;
  const int lane = tid & 63;
  const int wave = tid >> 6;

  const int row = rb * 32 + (tid >> 5);
  const int cg = tid & 31;  // cols cg*4 .. cg*4+3

  const _Float16* sb = (const _Float16*)ws + (size_t)(p * KSPL) * GSZ;
  // fragment-major half-index of (row, cg*4)
  const int wv = ((row >> 5) << 2) + (cg >> 3);
  const int a = (((row >> 4) & 1) << 1) + ((cg >> 2) & 1);
  const int ln = (((row & 15) >> 2) << 4) + ((cg & 3) << 2);
  const int idx = wv * 1024 + a * 256 + ln * 4 + (row & 3);

  float g0 = 0.f, g1 = 0.f, g2 = 0.f, g3 = 0.f;
#pragma unroll
  for (int c8 = 0; c8 < KSPL; ++c8) {
    const _Float16* bp = sb + (size_t)c8 * GSZ + idx;
    g0 += (float)bp[0]; g1 += (float)bp[4]; g2 += (float)bp[8]; g3 += (float)bp[12];
  }

  // diagonal (sq): same fp16 values + same sum order as strips -> l2_ii exactly 0
  if (tid < NROW) {
    const int i = tid;
    const int wd = (i >> 5) * 5;
    const int ad = ((i >> 4) & 1) * 3;
    const int lnd = (((i & 15) >> 2) << 4) + (i & 15);
    const int idxd = wd * 1024 + ad * 256 + lnd * 4 + (i & 3);
    float d = 0.0f;
#pragma unroll
    for (int c8 = 0; c8 < KSPL; ++c8) d += (float)sb[(size_t)c8 * GSZ + idxd];
    sqv[i] = d;
  }
  if (tid < 2) quad2[tid] = 0.0f;
  __syncthreads();

  if (tid == 0) {
    float ssq = 0.0f;
    for (int i = 0; i < NROW; ++i) ssq += sqv[i];
    float gt = ws[GT2F_OFF + p * 4 + 0] + ws[GT2F_OFF + p * 4 + 1] +
               ws[GT2F_OFF + p * 4 + 2] + ws[GT2F_OFF + p * 4 + 3];
    float suml2 = 2.0f * (float)NROW * ssq - 2.0f * gt;      // sum(l2) identity
    float bw = suml2 / (float)(NROW * NROW - NROW) * 0.25f;  // /(n^2-n) /KERNEL_MUL^2
    float mult = 1.0f;
    for (int k = 0; k < 5; ++k) {
      bcast[k] = 1.0f / (bw * mult + 1e-9f);
      mult *= 2.0f;
    }
  }
  __syncthreads();

  const float sqi = sqv[row];
  float l2r[4];
  float lmax = 0.0f;
  {
    const float gg[4] = {g0, g1, g2, g3};
#pragma unroll
    for (int k = 0; k < 4; ++k) {
      float v = sqi + sqv[cg * 4 + k] - 2.0f * gg[k];
      l2r[k] = v;
      lmax = fmaxf(lmax, v);
    }
  }
#pragma unroll
  for (int m = 1; m <= 32; m <<= 1) lmax = fmaxf(lmax, __shfl_xor(lmax, m, 64));
  if (lane == 0) redm[wave] = lmax;

  const float ib0 = bcast[0], ib1 = bcast[1], ib2 = bcast[2], ib3 = bcast[3], ib4 = bcast[4];
  float qsum = 0.0f;
#pragma unroll
  for (int k = 0; k < 4; ++k) {
    float v = l2r[k];
    qsum += __expf(-v * ib0) + __expf(-v * ib1) + __expf(-v * ib2) +
            __expf(-v * ib3) + __expf(-v * ib4);
  }
  // lanes with bit4=0: col-half X; bit4=1: col-half Y
  qsum += __shfl_xor(qsum, 1, 64);
  qsum += __shfl_xor(qsum, 2, 64);
  qsum += __shfl_xor(qsum, 4, 64);
  qsum += __shfl_xor(qsum, 8, 64);
  qsum += __shfl_xor(qsum, 32, 64);
  if (lane == 0) atomicAdd(&quad2[0], qsum);   // LDS atomic, cols X
  if (lane == 16) atomicAdd(&quad2[1], qsum);  // LDS atomic, cols Y
  __syncthreads();

  if (tid == 0) {
    float mx = 0.0f;
    for (int w = 0; w < 16; ++w) mx = fmaxf(mx, redm[w]);
    float4* part = (float4*)(ws + PART_OFF);
    part[b] = make_float4(quad2[0], quad2[1], mx, 0.0f);
  }
}

// ---- Kernel C: combine 256 reduce-block partials, write all 6 outputs. grid = 1.
__global__ __launch_bounds__(256) void final_kernel(const float* __restrict__ ws,
                                                    float* __restrict__ out) {
  __shared__ float fr2[4][5];
  const int tid = threadIdx.x;
  const int lane = tid & 63;
  const int wave = tid >> 6;
  const float4* part = (const float4*)(ws + PART_OFF);
  float4 pt = part[tid];
  const int rb = tid & 3;
  float xx = (rb < 2) ? pt.x : 0.0f;
  float xy = (rb < 2) ? pt.y : 0.0f;
  float yx = (rb >= 2) ? pt.x : 0.0f;
  float yy = (rb >= 2) ? pt.y : 0.0f;
  float mx = ((tid >> 2) == NSPLIT - 1) ? pt.z : 0.0f;
#pragma unroll
  for (int m = 1; m <= 32; m <<= 1) {
    xx += __shfl_xor(xx, m, 64);
    xy += __shfl_xor(xy, m, 64);
    yx += __shfl_xor(yx, m, 64);
    yy += __shfl_xor(yy, m, 64);
    mx = fmaxf(mx, __shfl_xor(mx, m, 64));
  }
  if (lane == 0) {
    fr2[wave][0] = xx; fr2[wave][1] = xy; fr2[wave][2] = yx; fr2[wave][3] = yy; fr2[wave][4] = mx;
  }
  __syncthreads();
  if (tid == 0) {
    float sxx = 0, sxy = 0, syx = 0, syy = 0, smx = 0;
    for (int w = 0; w < 4; ++w) {
      sxx += fr2[w][0]; sxy += fr2[w][1]; syx += fr2[w][2]; syy += fr2[w][3];
      smx = fmaxf(smx, fr2[w][4]);
    }
    const float inv = 1.0f / (4096.0f * 64.0f);  // /(64*64) then /P
    out[0] = (sxx + syy - sxy - syx) * inv;
    out[1] = smx;
    out[2] = sxx * inv;
    out[3] = syy * inv;
    out[4] = sxy * inv;
    out[5] = syx * inv;
  }
}

extern "C" void kernel_launch(void* const* d_in, const int* in_sizes, int n_in,
                              void* d_out, int out_size, void* d_ws, size_t ws_size,
                              hipStream_t stream) {
  const float* src = (const float*)d_in[0];
  const float* tgt = (const float*)d_in[1];
  float* out = (float*)d_out;
  float* ws = (float*)d_ws;  // fp16 slabs 8.4 MB + gsum + partials
  gram_kernel<<<NBLK, 1024, 0, stream>>>(src, tgt, ws);
  reduce_kernel<<<NBLK, 1024, 0, stream>>>(ws, out);
  final_kernel<<<1, 256, 0, stream>>>(ws, out);
}